// Round 1
// baseline (144.495 us; speedup 1.0000x reference)
//
#include <hip/hip_runtime.h>
#include <hip/hip_bf16.h>

#define DIM 384
#define NBLK 3
#define BATCH 1024

// ---------------------------------------------------------------------------
// Kernel 1: precompute Prw[i][j] = rw[i] * prod_k(1 - W_k[i][j])
//           qconst[j] += rw[i] * (b0*(1-w1)*(1-w2) + b1*(1-w2) + b2)
// ---------------------------------------------------------------------------
__global__ void precompute_kernel(const float* __restrict__ W,
                                  const float* __restrict__ Bb,
                                  const float* __restrict__ rw,
                                  float* __restrict__ Prw,
                                  float* __restrict__ qconst) {
    int idx = blockIdx.x * blockDim.x + threadIdx.x;   // 0 .. DIM*DIM-1
    if (idx >= DIM * DIM) return;
    int i = idx / DIM;
    int j = idx - i * DIM;
    const int S = DIM * DIM;
    float w0 = W[idx], w1 = W[S + idx], w2 = W[2 * S + idx];
    float b0 = Bb[idx], b1 = Bb[S + idx], b2 = Bb[2 * S + idx];
    float r1 = 1.0f - w1, r2 = 1.0f - w2;
    float p = (1.0f - w0) * r1 * r2;
    float q = b0 * r1 * r2 + b1 * r2 + b2;
    float r = rw[i];
    Prw[idx] = r * p;
    float rq = r * q;
    // lanes within a wave hit distinct j -> no intra-wave contention
    atomicAdd(&qconst[j], rq);
    (void)j;
}

// ---------------------------------------------------------------------------
// Kernel 2: t = v1 @ Prw  (A: BATCH x DIM row-major, B: DIM x DIM row-major)
//           pooled[b][j] = v2[b][j] * t[b][j] - qconst[j]
// ---------------------------------------------------------------------------
#define BM 32
#define BN 32
#define BK 32

__global__ __launch_bounds__(256)
void gemm1_kernel(const float* __restrict__ A,     // v1
                  const float* __restrict__ Bm,    // Prw
                  const float* __restrict__ v2,
                  const float* __restrict__ qc,
                  float* __restrict__ pooled) {
    __shared__ float As[BM][BK + 1];
    __shared__ float Bs[BK][BN + 1];
    const int bn = blockIdx.x * BN;   // output col (j)
    const int bm = blockIdx.y * BM;   // output row (batch)
    const int tid = threadIdx.x;      // 0..255
    const int tr = tid >> 4;          // 0..15
    const int tc = tid & 15;          // 0..15
    float acc00 = 0.f, acc01 = 0.f, acc10 = 0.f, acc11 = 0.f;

    for (int k0 = 0; k0 < DIM; k0 += BK) {
        #pragma unroll
        for (int l = tid; l < BM * BK; l += 256) {
            int r = l >> 5, c = l & 31;
            As[r][c] = A[(bm + r) * DIM + k0 + c];
        }
        #pragma unroll
        for (int l = tid; l < BK * BN; l += 256) {
            int r = l >> 5, c = l & 31;
            Bs[r][c] = Bm[(k0 + r) * DIM + bn + c];
        }
        __syncthreads();
        #pragma unroll
        for (int k = 0; k < BK; ++k) {
            float a0 = As[tr * 2][k];
            float a1 = As[tr * 2 + 1][k];
            float b0 = Bs[k][tc * 2];
            float b1 = Bs[k][tc * 2 + 1];
            acc00 += a0 * b0; acc01 += a0 * b1;
            acc10 += a1 * b0; acc11 += a1 * b1;
        }
        __syncthreads();
    }

    int b0r = bm + tr * 2, b1r = b0r + 1;
    int j0 = bn + tc * 2, j1 = j0 + 1;
    float q0 = qc[j0], q1 = qc[j1];
    pooled[b0r * DIM + j0] = v2[b0r * DIM + j0] * acc00 - q0;
    pooled[b0r * DIM + j1] = v2[b0r * DIM + j1] * acc01 - q1;
    pooled[b1r * DIM + j0] = v2[b1r * DIM + j0] * acc10 - q0;
    pooled[b1r * DIM + j1] = v2[b1r * DIM + j1] * acc11 - q1;
}

// ---------------------------------------------------------------------------
// Kernel 3: out = pooled @ lin_W^T + lin_b
//           out[b][n] = sum_j pooled[b][j] * lin_W[n][j] + lin_b[n]
// ---------------------------------------------------------------------------
__global__ __launch_bounds__(256)
void gemm2_kernel(const float* __restrict__ A,     // pooled
                  const float* __restrict__ Wl,    // lin_W (DIM x DIM), row n contiguous in j
                  const float* __restrict__ bl,    // lin_b
                  float* __restrict__ out) {
    __shared__ float As[BM][BK + 1];
    __shared__ float Bs[BK][BN + 1];   // Bs[k][n] = Wl[n][k]
    const int bn = blockIdx.x * BN;   // output col (n)
    const int bm = blockIdx.y * BM;   // output row (batch)
    const int tid = threadIdx.x;
    const int tr = tid >> 4;
    const int tc = tid & 15;
    float acc00 = 0.f, acc01 = 0.f, acc10 = 0.f, acc11 = 0.f;

    for (int k0 = 0; k0 < DIM; k0 += BK) {
        #pragma unroll
        for (int l = tid; l < BM * BK; l += 256) {
            int r = l >> 5, c = l & 31;
            As[r][c] = A[(bm + r) * DIM + k0 + c];
        }
        // load lin_W tile transposed: consecutive threads read consecutive k
        #pragma unroll
        for (int l = tid; l < BN * BK; l += 256) {
            int c = l >> 5;        // n within tile
            int r = l & 31;        // k within tile
            Bs[r][c] = Wl[(bn + c) * DIM + k0 + r];
        }
        __syncthreads();
        #pragma unroll
        for (int k = 0; k < BK; ++k) {
            float a0 = As[tr * 2][k];
            float a1 = As[tr * 2 + 1][k];
            float b0 = Bs[k][tc * 2];
            float b1 = Bs[k][tc * 2 + 1];
            acc00 += a0 * b0; acc01 += a0 * b1;
            acc10 += a1 * b0; acc11 += a1 * b1;
        }
        __syncthreads();
    }

    int b0r = bm + tr * 2, b1r = b0r + 1;
    int n0 = bn + tc * 2, n1 = n0 + 1;
    float l0 = bl[n0], l1 = bl[n1];
    out[b0r * DIM + n0] = acc00 + l0;
    out[b0r * DIM + n1] = acc01 + l1;
    out[b1r * DIM + n0] = acc10 + l0;
    out[b1r * DIM + n1] = acc11 + l1;
}

extern "C" void kernel_launch(void* const* d_in, const int* in_sizes, int n_in,
                              void* d_out, int out_size, void* d_ws, size_t ws_size,
                              hipStream_t stream) {
    const float* v1  = (const float*)d_in[0];
    const float* v2  = (const float*)d_in[1];
    const float* bW  = (const float*)d_in[2];
    const float* bB  = (const float*)d_in[3];
    const float* rw  = (const float*)d_in[4];
    const float* lW  = (const float*)d_in[5];
    const float* lb  = (const float*)d_in[6];
    float* out = (float*)d_out;

    float* ws = (float*)d_ws;
    float* Prw    = ws;                       // DIM*DIM
    float* qconst = ws + DIM * DIM;           // DIM
    float* pooled = ws + DIM * DIM + DIM;     // BATCH*DIM

    hipMemsetAsync(qconst, 0, DIM * sizeof(float), stream);

    precompute_kernel<<<(DIM * DIM + 255) / 256, 256, 0, stream>>>(bW, bB, rw, Prw, qconst);

    dim3 g1(DIM / BN, BATCH / BM);
    gemm1_kernel<<<g1, 256, 0, stream>>>(v1, Prw, v2, qconst, pooled);

    dim3 g2(DIM / BN, BATCH / BM);
    gemm2_kernel<<<g2, 256, 0, stream>>>(pooled, lW, lb, out);
}

// Round 2
// 141.545 us; speedup vs baseline: 1.0208x; 1.0208x over previous
//
#include <hip/hip_runtime.h>
#include <hip/hip_bf16.h>

#define DIM 384
#define BATCH 1024
#define SPLANE (DIM * DIM)

// ---------------------------------------------------------------------------
// Kernel 1: Prw[i][j] = rw[i] * (1-W0[i][j])(1-W1[i][j])(1-W2[i][j])
// Pure streaming, no atomics. 576 blocks x 256 = DIM*DIM threads exactly.
// ---------------------------------------------------------------------------
__global__ __launch_bounds__(256)
void prw_kernel(const float* __restrict__ W,
                const float* __restrict__ rw,
                float* __restrict__ Prw) {
    int idx = blockIdx.x * 256 + threadIdx.x;    // < DIM*DIM by construction
    int i = idx / DIM;
    float w0 = W[idx], w1 = W[SPLANE + idx], w2 = W[2 * SPLANE + idx];
    Prw[idx] = rw[i] * (1.0f - w0) * (1.0f - w1) * (1.0f - w2);
}

// ---------------------------------------------------------------------------
// Kernel 2: qconst[j] = sum_i rw[i] * (b0*(1-w1)*(1-w2) + b1*(1-w2) + b2)
// Thread j sums the column; for each i, threads j,j+1,... read consecutive
// addresses -> fully coalesced. No atomics, no memset. 3 blocks x 128.
// ---------------------------------------------------------------------------
__global__ __launch_bounds__(128)
void qconst_kernel(const float* __restrict__ W,
                   const float* __restrict__ Bb,
                   const float* __restrict__ rw,
                   float* __restrict__ qc) {
    int j = blockIdx.x * 128 + threadIdx.x;      // 0..DIM-1
    float s = 0.0f;
    #pragma unroll 4
    for (int i = 0; i < DIM; ++i) {
        int idx = i * DIM + j;
        float r1 = 1.0f - W[SPLANE + idx];
        float r2 = 1.0f - W[2 * SPLANE + idx];
        float q = Bb[idx] * r1 * r2 + Bb[SPLANE + idx] * r2 + Bb[2 * SPLANE + idx];
        s += rw[i] * q;
    }
    qc[j] = s;
}

// ---------------------------------------------------------------------------
// GEMM tiles: BM=32 (batch rows), BN=64 (cols), BK=32. 256 threads.
// Microtile 2x4 per thread. A stored k-major (transposed) in LDS so the
// per-k A read is one ds_read_b64 (broadcast across 16 lanes); B read is one
// ds_read_b128. Register-prefetch double buffering hides global latency.
// ---------------------------------------------------------------------------
#define BM 32
#define BN 64
#define BK 32
#define APAD 34   // even stride -> 8B-aligned float2 reads at Ast[k][2*tr]
#define BPAD 68   // multiple of 4 -> 16B-aligned float4 reads

// Kernel 3: t = v1 @ Prw ; pooled = v2 .* t - qconst (broadcast over rows)
__global__ __launch_bounds__(256)
void gemm1_kernel(const float* __restrict__ A,     // v1   (BATCH x DIM)
                  const float* __restrict__ Bm,    // Prw  (DIM x DIM)
                  const float* __restrict__ v2,
                  const float* __restrict__ qc,
                  float* __restrict__ pooled) {
    __shared__ float Ast[BK][APAD];   // Ast[k][r]
    __shared__ float Bs[BK][BPAD];    // Bs[k][n]
    const int bn = blockIdx.x * BN;
    const int bm = blockIdx.y * BM;
    const int tid = threadIdx.x;
    const int tc = tid & 15;          // 4 cols: 4*tc..4*tc+3
    const int tr = tid >> 4;          // 2 rows: 2*tr, 2*tr+1

    // global-load assignments
    const int ar  = tid >> 3;         // 0..31  (A row within tile)
    const int ak4 = (tid & 7) * 4;    // k offset, float4
    const int br  = tid >> 4;         // 0..15  (B k-row; also +16)
    const int bn4 = (tid & 15) * 4;   // n offset, float4

    const float* Aptr = A + (bm + ar) * DIM + ak4;
    const float* Bptr = Bm + br * DIM + bn + bn4;

    float4 pa  = *(const float4*)Aptr;
    float4 pb0 = *(const float4*)Bptr;
    float4 pb1 = *(const float4*)(Bptr + 16 * DIM);

    float acc[2][4] = {{0,0,0,0},{0,0,0,0}};

    const int NT = DIM / BK;          // 12
    for (int t = 0; t < NT; ++t) {
        // write prefetched regs to LDS
        Ast[ak4 + 0][ar] = pa.x;
        Ast[ak4 + 1][ar] = pa.y;
        Ast[ak4 + 2][ar] = pa.z;
        Ast[ak4 + 3][ar] = pa.w;
        *(float4*)&Bs[br][bn4]      = pb0;
        *(float4*)&Bs[br + 16][bn4] = pb1;
        __syncthreads();

        // prefetch next tile
        if (t + 1 < NT) {
            const float* An = Aptr + (t + 1) * BK;
            const float* Bn = Bptr + (t + 1) * BK * DIM;
            pa  = *(const float4*)An;
            pb0 = *(const float4*)Bn;
            pb1 = *(const float4*)(Bn + 16 * DIM);
        }

        #pragma unroll
        for (int k = 0; k < BK; ++k) {
            float2 a = *(const float2*)&Ast[k][2 * tr];
            float4 b = *(const float4*)&Bs[k][4 * tc];
            acc[0][0] += a.x * b.x; acc[0][1] += a.x * b.y;
            acc[0][2] += a.x * b.z; acc[0][3] += a.x * b.w;
            acc[1][0] += a.y * b.x; acc[1][1] += a.y * b.y;
            acc[1][2] += a.y * b.z; acc[1][3] += a.y * b.w;
        }
        __syncthreads();
    }

    const int b0 = bm + 2 * tr;
    const int j0 = bn + 4 * tc;
    float4 q  = *(const float4*)&qc[j0];
    float4 v0 = *(const float4*)&v2[b0 * DIM + j0];
    float4 v1r = *(const float4*)&v2[(b0 + 1) * DIM + j0];
    float4 o0, o1;
    o0.x = v0.x * acc[0][0] - q.x;  o0.y = v0.y * acc[0][1] - q.y;
    o0.z = v0.z * acc[0][2] - q.z;  o0.w = v0.w * acc[0][3] - q.w;
    o1.x = v1r.x * acc[1][0] - q.x; o1.y = v1r.y * acc[1][1] - q.y;
    o1.z = v1r.z * acc[1][2] - q.z; o1.w = v1r.w * acc[1][3] - q.w;
    *(float4*)&pooled[b0 * DIM + j0]       = o0;
    *(float4*)&pooled[(b0 + 1) * DIM + j0] = o1;
}

// Kernel 4: out = pooled @ lin_W^T + lin_b
// Bs[k][n] = lin_W[n][k]  (transposed into LDS; global reads coalesced
// along k which is contiguous in lin_W's rows)
__global__ __launch_bounds__(256)
void gemm2_kernel(const float* __restrict__ A,     // pooled (BATCH x DIM)
                  const float* __restrict__ Wl,    // lin_W  (DIM x DIM)
                  const float* __restrict__ bl,    // lin_b
                  float* __restrict__ out) {
    __shared__ float Ast[BK][APAD];
    __shared__ float Bs[BK][BPAD];
    const int bn = blockIdx.x * BN;
    const int bm = blockIdx.y * BM;
    const int tid = threadIdx.x;
    const int tc = tid & 15;
    const int tr = tid >> 4;

    const int ar  = tid >> 3;
    const int ak4 = (tid & 7) * 4;
    const int ln  = tid >> 3;         // 0..31 (B col n; also +32)
    const int lk4 = (tid & 7) * 4;    // k offset, float4 along lin_W row

    const float* Aptr = A + (bm + ar) * DIM + ak4;
    const float* Wptr = Wl + (bn + ln) * DIM + lk4;

    float4 pa  = *(const float4*)Aptr;
    float4 pw0 = *(const float4*)Wptr;
    float4 pw1 = *(const float4*)(Wptr + 32 * DIM);

    float acc[2][4] = {{0,0,0,0},{0,0,0,0}};

    const int NT = DIM / BK;
    for (int t = 0; t < NT; ++t) {
        Ast[ak4 + 0][ar] = pa.x;
        Ast[ak4 + 1][ar] = pa.y;
        Ast[ak4 + 2][ar] = pa.z;
        Ast[ak4 + 3][ar] = pa.w;
        Bs[lk4 + 0][ln] = pw0.x;  Bs[lk4 + 0][ln + 32] = pw1.x;
        Bs[lk4 + 1][ln] = pw0.y;  Bs[lk4 + 1][ln + 32] = pw1.y;
        Bs[lk4 + 2][ln] = pw0.z;  Bs[lk4 + 2][ln + 32] = pw1.z;
        Bs[lk4 + 3][ln] = pw0.w;  Bs[lk4 + 3][ln + 32] = pw1.w;
        __syncthreads();

        if (t + 1 < NT) {
            const float* An = Aptr + (t + 1) * BK;
            const float* Wn = Wptr + (t + 1) * BK;
            pa  = *(const float4*)An;
            pw0 = *(const float4*)Wn;
            pw1 = *(const float4*)(Wn + 32 * DIM);
        }

        #pragma unroll
        for (int k = 0; k < BK; ++k) {
            float2 a = *(const float2*)&Ast[k][2 * tr];
            float4 b = *(const float4*)&Bs[k][4 * tc];
            acc[0][0] += a.x * b.x; acc[0][1] += a.x * b.y;
            acc[0][2] += a.x * b.z; acc[0][3] += a.x * b.w;
            acc[1][0] += a.y * b.x; acc[1][1] += a.y * b.y;
            acc[1][2] += a.y * b.z; acc[1][3] += a.y * b.w;
        }
        __syncthreads();
    }

    const int b0 = bm + 2 * tr;
    const int n0 = bn + 4 * tc;
    float4 lbv = *(const float4*)&bl[n0];
    float4 o0, o1;
    o0.x = acc[0][0] + lbv.x; o0.y = acc[0][1] + lbv.y;
    o0.z = acc[0][2] + lbv.z; o0.w = acc[0][3] + lbv.w;
    o1.x = acc[1][0] + lbv.x; o1.y = acc[1][1] + lbv.y;
    o1.z = acc[1][2] + lbv.z; o1.w = acc[1][3] + lbv.w;
    *(float4*)&out[b0 * DIM + n0]       = o0;
    *(float4*)&out[(b0 + 1) * DIM + n0] = o1;
}

extern "C" void kernel_launch(void* const* d_in, const int* in_sizes, int n_in,
                              void* d_out, int out_size, void* d_ws, size_t ws_size,
                              hipStream_t stream) {
    const float* v1  = (const float*)d_in[0];
    const float* v2  = (const float*)d_in[1];
    const float* bW  = (const float*)d_in[2];
    const float* bB  = (const float*)d_in[3];
    const float* rw  = (const float*)d_in[4];
    const float* lW  = (const float*)d_in[5];
    const float* lb  = (const float*)d_in[6];
    float* out = (float*)d_out;

    float* ws = (float*)d_ws;
    float* Prw    = ws;                         // DIM*DIM
    float* qconst = ws + SPLANE;                // DIM
    float* pooled = ws + SPLANE + DIM;          // BATCH*DIM

    prw_kernel<<<SPLANE / 256, 256, 0, stream>>>(bW, rw, Prw);
    qconst_kernel<<<DIM / 128, 128, 0, stream>>>(bW, bB, rw, qconst);

    dim3 g(DIM / BN, BATCH / BM);               // 6 x 32 = 192 blocks
    gemm1_kernel<<<g, 256, 0, stream>>>(v1, Prw, v2, qconst, pooled);
    gemm2_kernel<<<g, 256, 0, stream>>>(pooled, lW, lb, out);
}

// Round 3
// 98.577 us; speedup vs baseline: 1.4658x; 1.4359x over previous
//
#include <hip/hip_runtime.h>
#include <hip/hip_bf16.h>

#define DIM 384
#define BATCH 1024
#define SPLANE (DIM * DIM)

// ---------------------------------------------------------------------------
// Kernel A (fused weight prep):
//   Prw[i][j] = rw[i] * (1-W0[i][j])(1-W1[i][j])(1-W2[i][j])
//   qc[j]    += sum_i rw[i] * (b0*(1-w1)*(1-w2) + b1*(1-w2) + b2)
// Grid (3 j-blocks, 64 i-blocks) x 128 threads; each thread covers 6 i's for
// one j. All loads coalesced over j; 64 atomicAdds per qc address total.
// qc must be zeroed beforehand (memsetAsync in kernel_launch).
// ---------------------------------------------------------------------------
__global__ __launch_bounds__(128)
void prep_kernel(const float* __restrict__ W,
                 const float* __restrict__ Bb,
                 const float* __restrict__ rw,
                 float* __restrict__ Prw,
                 float* __restrict__ qc) {
    const int j  = blockIdx.x * 128 + threadIdx.x;   // 0..DIM-1
    const int i0 = blockIdx.y * 6;                   // 64 blocks * 6 = DIM
    float s = 0.0f;
    #pragma unroll
    for (int ii = 0; ii < 6; ++ii) {
        const int i = i0 + ii;
        const int idx = i * DIM + j;
        float w0 = W[idx], w1 = W[SPLANE + idx], w2 = W[2 * SPLANE + idx];
        float b0 = Bb[idx], b1 = Bb[SPLANE + idx], b2 = Bb[2 * SPLANE + idx];
        float r1 = 1.0f - w1, r2 = 1.0f - w2;
        float r = rw[i];
        Prw[idx] = r * (1.0f - w0) * r1 * r2;
        s += r * (b0 * r1 * r2 + b1 * r2 + b2);
    }
    atomicAdd(&qc[j], s);
}

// ---------------------------------------------------------------------------
// GEMM tiles: BM=32 (batch rows), BN=64 (cols), BK=32. 256 threads.
// Microtile 2x4 per thread. A stored k-major (transposed) in LDS so the
// per-k A read is one ds_read_b64 (broadcast across 16 lanes); B read is one
// ds_read_b128. Register-prefetch double buffering hides global latency.
// ---------------------------------------------------------------------------
#define BM 32
#define BN 64
#define BK 32
#define APAD 34   // even stride -> 8B-aligned float2 reads at Ast[k][2*tr]
#define BPAD 68   // multiple of 4 -> 16B-aligned float4 reads

// Kernel B: t = v1 @ Prw ; pooled = v2 .* t - qconst (broadcast over rows)
__global__ __launch_bounds__(256)
void gemm1_kernel(const float* __restrict__ A,     // v1   (BATCH x DIM)
                  const float* __restrict__ Bm,    // Prw  (DIM x DIM)
                  const float* __restrict__ v2,
                  const float* __restrict__ qc,
                  float* __restrict__ pooled) {
    __shared__ float Ast[BK][APAD];   // Ast[k][r]
    __shared__ float Bs[BK][BPAD];    // Bs[k][n]
    const int bn = blockIdx.x * BN;
    const int bm = blockIdx.y * BM;
    const int tid = threadIdx.x;
    const int tc = tid & 15;          // 4 cols: 4*tc..4*tc+3
    const int tr = tid >> 4;          // 2 rows: 2*tr, 2*tr+1

    const int ar  = tid >> 3;         // 0..31  (A row within tile)
    const int ak4 = (tid & 7) * 4;    // k offset, float4
    const int br  = tid >> 4;         // 0..15  (B k-row; also +16)
    const int bn4 = (tid & 15) * 4;   // n offset, float4

    const float* Aptr = A + (bm + ar) * DIM + ak4;
    const float* Bptr = Bm + br * DIM + bn + bn4;

    float4 pa  = *(const float4*)Aptr;
    float4 pb0 = *(const float4*)Bptr;
    float4 pb1 = *(const float4*)(Bptr + 16 * DIM);

    float acc[2][4] = {{0,0,0,0},{0,0,0,0}};

    const int NT = DIM / BK;          // 12
    for (int t = 0; t < NT; ++t) {
        Ast[ak4 + 0][ar] = pa.x;
        Ast[ak4 + 1][ar] = pa.y;
        Ast[ak4 + 2][ar] = pa.z;
        Ast[ak4 + 3][ar] = pa.w;
        *(float4*)&Bs[br][bn4]      = pb0;
        *(float4*)&Bs[br + 16][bn4] = pb1;
        __syncthreads();

        if (t + 1 < NT) {
            const float* An = Aptr + (t + 1) * BK;
            const float* Bn = Bptr + (t + 1) * BK * DIM;
            pa  = *(const float4*)An;
            pb0 = *(const float4*)Bn;
            pb1 = *(const float4*)(Bn + 16 * DIM);
        }

        #pragma unroll
        for (int k = 0; k < BK; ++k) {
            float2 a = *(const float2*)&Ast[k][2 * tr];
            float4 b = *(const float4*)&Bs[k][4 * tc];
            acc[0][0] += a.x * b.x; acc[0][1] += a.x * b.y;
            acc[0][2] += a.x * b.z; acc[0][3] += a.x * b.w;
            acc[1][0] += a.y * b.x; acc[1][1] += a.y * b.y;
            acc[1][2] += a.y * b.z; acc[1][3] += a.y * b.w;
        }
        __syncthreads();
    }

    const int b0 = bm + 2 * tr;
    const int j0 = bn + 4 * tc;
    float4 q  = *(const float4*)&qc[j0];
    float4 v0 = *(const float4*)&v2[b0 * DIM + j0];
    float4 v1r = *(const float4*)&v2[(b0 + 1) * DIM + j0];
    float4 o0, o1;
    o0.x = v0.x * acc[0][0] - q.x;  o0.y = v0.y * acc[0][1] - q.y;
    o0.z = v0.z * acc[0][2] - q.z;  o0.w = v0.w * acc[0][3] - q.w;
    o1.x = v1r.x * acc[1][0] - q.x; o1.y = v1r.y * acc[1][1] - q.y;
    o1.z = v1r.z * acc[1][2] - q.z; o1.w = v1r.w * acc[1][3] - q.w;
    *(float4*)&pooled[b0 * DIM + j0]       = o0;
    *(float4*)&pooled[(b0 + 1) * DIM + j0] = o1;
}

// Kernel C: out = pooled @ lin_W^T + lin_b
__global__ __launch_bounds__(256)
void gemm2_kernel(const float* __restrict__ A,     // pooled (BATCH x DIM)
                  const float* __restrict__ Wl,    // lin_W  (DIM x DIM)
                  const float* __restrict__ bl,    // lin_b
                  float* __restrict__ out) {
    __shared__ float Ast[BK][APAD];
    __shared__ float Bs[BK][BPAD];
    const int bn = blockIdx.x * BN;
    const int bm = blockIdx.y * BM;
    const int tid = threadIdx.x;
    const int tc = tid & 15;
    const int tr = tid >> 4;

    const int ar  = tid >> 3;
    const int ak4 = (tid & 7) * 4;
    const int ln  = tid >> 3;         // 0..31 (B col n; also +32)
    const int lk4 = (tid & 7) * 4;    // k offset, float4 along lin_W row

    const float* Aptr = A + (bm + ar) * DIM + ak4;
    const float* Wptr = Wl + (bn + ln) * DIM + lk4;

    float4 pa  = *(const float4*)Aptr;
    float4 pw0 = *(const float4*)Wptr;
    float4 pw1 = *(const float4*)(Wptr + 32 * DIM);

    float acc[2][4] = {{0,0,0,0},{0,0,0,0}};

    const int NT = DIM / BK;
    for (int t = 0; t < NT; ++t) {
        Ast[ak4 + 0][ar] = pa.x;
        Ast[ak4 + 1][ar] = pa.y;
        Ast[ak4 + 2][ar] = pa.z;
        Ast[ak4 + 3][ar] = pa.w;
        Bs[lk4 + 0][ln] = pw0.x;  Bs[lk4 + 0][ln + 32] = pw1.x;
        Bs[lk4 + 1][ln] = pw0.y;  Bs[lk4 + 1][ln + 32] = pw1.y;
        Bs[lk4 + 2][ln] = pw0.z;  Bs[lk4 + 2][ln + 32] = pw1.z;
        Bs[lk4 + 3][ln] = pw0.w;  Bs[lk4 + 3][ln + 32] = pw1.w;
        __syncthreads();

        if (t + 1 < NT) {
            const float* An = Aptr + (t + 1) * BK;
            const float* Wn = Wptr + (t + 1) * BK;
            pa  = *(const float4*)An;
            pw0 = *(const float4*)Wn;
            pw1 = *(const float4*)(Wn + 32 * DIM);
        }

        #pragma unroll
        for (int k = 0; k < BK; ++k) {
            float2 a = *(const float2*)&Ast[k][2 * tr];
            float4 b = *(const float4*)&Bs[k][4 * tc];
            acc[0][0] += a.x * b.x; acc[0][1] += a.x * b.y;
            acc[0][2] += a.x * b.z; acc[0][3] += a.x * b.w;
            acc[1][0] += a.y * b.x; acc[1][1] += a.y * b.y;
            acc[1][2] += a.y * b.z; acc[1][3] += a.y * b.w;
        }
        __syncthreads();
    }

    const int b0 = bm + 2 * tr;
    const int n0 = bn + 4 * tc;
    float4 lbv = *(const float4*)&bl[n0];
    float4 o0, o1;
    o0.x = acc[0][0] + lbv.x; o0.y = acc[0][1] + lbv.y;
    o0.z = acc[0][2] + lbv.z; o0.w = acc[0][3] + lbv.w;
    o1.x = acc[1][0] + lbv.x; o1.y = acc[1][1] + lbv.y;
    o1.z = acc[1][2] + lbv.z; o1.w = acc[1][3] + lbv.w;
    *(float4*)&out[b0 * DIM + n0]       = o0;
    *(float4*)&out[(b0 + 1) * DIM + n0] = o1;
}

extern "C" void kernel_launch(void* const* d_in, const int* in_sizes, int n_in,
                              void* d_out, int out_size, void* d_ws, size_t ws_size,
                              hipStream_t stream) {
    const float* v1  = (const float*)d_in[0];
    const float* v2  = (const float*)d_in[1];
    const float* bW  = (const float*)d_in[2];
    const float* bB  = (const float*)d_in[3];
    const float* rw  = (const float*)d_in[4];
    const float* lW  = (const float*)d_in[5];
    const float* lb  = (const float*)d_in[6];
    float* out = (float*)d_out;

    float* ws = (float*)d_ws;
    float* Prw    = ws;                         // DIM*DIM
    float* qconst = ws + SPLANE;                // DIM
    float* pooled = ws + SPLANE + DIM;          // BATCH*DIM

    hipMemsetAsync(qconst, 0, DIM * sizeof(float), stream);

    dim3 gp(DIM / 128, DIM / 6);                // (3, 64) = 192 blocks
    prep_kernel<<<gp, 128, 0, stream>>>(bW, bB, rw, Prw, qconst);

    dim3 g(DIM / BN, BATCH / BM);               // 6 x 32 = 192 blocks
    gemm1_kernel<<<g, 256, 0, stream>>>(v1, Prw, v2, qconst, pooled);
    gemm2_kernel<<<g, 256, 0, stream>>>(pooled, lW, lb, out);
}